// Round 1
// baseline (359.483 us; speedup 1.0000x reference)
//
#include <hip/hip_runtime.h>
#include <hip/hip_bf16.h>

#define IN_F 8192
#define OUT_F 8192
#define STATE_THRESHOLD 50.0f

// One wave (64 lanes) per output row. Block = 256 threads = 4 waves = 4 rows.
// Spike vector staged in LDS once per block (32 KiB -> 5 blocks/CU LDS cap).
__global__ __launch_bounds__(256) void snn_gemv_kernel(
    const float* __restrict__ spike_input,      // [IN_F]
    const float* __restrict__ synapse_states,   // [OUT_F, IN_F]
    const float* __restrict__ membrane,         // [OUT_F]
    const float* __restrict__ adaptive_thresh,  // [OUT_F]
    const float* __restrict__ noise,            // [OUT_F]
    float* __restrict__ out)                    // [OUT_F]
{
    __shared__ float s_spike[IN_F];             // 32 KiB

    const int tid  = threadIdx.x;               // 0..255
    const int lane = tid & 63;
    const int wave = tid >> 6;                  // 0..3

    // Stage spike vector: 8192 floats = 2048 float4, 256 threads -> 8 each.
    const float4* sp4 = (const float4*)spike_input;
    float4* ls4 = (float4*)s_spike;
#pragma unroll
    for (int j = 0; j < 8; ++j) {
        ls4[tid + 256 * j] = sp4[tid + 256 * j];
    }
    __syncthreads();

    const int row = blockIdx.x * 4 + wave;
    const float4* rowp = (const float4*)(synapse_states + (size_t)row * IN_F);
    const float4* lsp  = (const float4*)s_spike;

    float acc = 0.0f;
    // 2048 float4 per row / 64 lanes = 32 iterations, coalesced 1 KiB/wave/load.
#pragma unroll 4
    for (int k = lane; k < IN_F / 4; k += 64) {
        float4 s = rowp[k];
        float4 x = lsp[k];
        acc += (s.x > STATE_THRESHOLD ? x.x : 0.0f);
        acc += (s.y > STATE_THRESHOLD ? x.y : 0.0f);
        acc += (s.z > STATE_THRESHOLD ? x.z : 0.0f);
        acc += (s.w > STATE_THRESHOLD ? x.w : 0.0f);
    }

    // Wave-level reduction across 64 lanes.
#pragma unroll
    for (int off = 32; off > 0; off >>= 1) {
        acc += __shfl_down(acc, off);
    }

    if (lane == 0) {
        float potential = membrane[row] + acc + noise[row];
        out[row] = (potential >= adaptive_thresh[row]) ? 1.0f : 0.0f;
    }
}

extern "C" void kernel_launch(void* const* d_in, const int* in_sizes, int n_in,
                              void* d_out, int out_size, void* d_ws, size_t ws_size,
                              hipStream_t stream) {
    const float* spike_input    = (const float*)d_in[0];
    const float* synapse_states = (const float*)d_in[1];
    const float* membrane       = (const float*)d_in[2];
    const float* adaptive_thr   = (const float*)d_in[3];
    const float* noise          = (const float*)d_in[4];
    float* out = (float*)d_out;

    dim3 grid(OUT_F / 4);   // 2048 blocks, 4 rows per block
    dim3 block(256);
    snn_gemv_kernel<<<grid, block, 0, stream>>>(
        spike_input, synapse_states, membrane, adaptive_thr, noise, out);
}